// Round 1
// baseline (175.228 us; speedup 1.0000x reference)
//
#include <hip/hip_runtime.h>
#include <math.h>

// Chamfer p-norm loss (P=5), B=8, N=M=4096, C=3.
// Strategy:
//  - argmin_j |q - r_j|^2  ==  argmin_j (|r_j|^2/2 - q.r_j)   (drop |q|^2)
//    -> precompute h_j = |r_j|^2/2 at LDS-stage time; inner loop = 3 FMA + argmin.
//  - sum_n pc^5 = sum_n sum_c |q_c - nn_c|^5  -> accumulate fifth powers directly,
//    one pow(., 0.2) per (batch, dir) at the end.
// Grid: 8 batches x 2 directions x 16 query-tiles = 256 blocks x 256 threads,
// one thread per query point. Ref points staged in LDS (float4, 2048/chunk = 32KB),
// wave-uniform LDS reads (broadcast, conflict-free).

#define BQ 256     // query points per block (= blockDim.x)
#define RT 2048    // reference points per LDS chunk (32 KB of float4)

__global__ __launch_bounds__(BQ) void chamfer_nn_kernel(
    const float* __restrict__ x, const float* __restrict__ y,
    float* __restrict__ acc, int N, int M)
{
    __shared__ float4 sref[RT];
    __shared__ float red[4];

    const int bid  = blockIdx.x;
    const int tile = bid & 15;         // 16 query tiles of 256
    const int dir  = (bid >> 4) & 1;   // 0: q=x ref=y, 1: q=y ref=x
    const int b    = bid >> 5;         // batch

    const float* Q;
    const float* R;
    int nr;
    if (dir == 0) {
        Q = x + (size_t)b * N * 3;
        R = y + (size_t)b * M * 3;
        nr = M;
    } else {
        Q = y + (size_t)b * M * 3;
        R = x + (size_t)b * N * 3;
        nr = N;
    }

    const int tid = threadIdx.x;
    const int q   = tile * BQ + tid;

    const float qx = Q[q * 3 + 0];
    const float qy = Q[q * 3 + 1];
    const float qz = Q[q * 3 + 2];

    float best  = 3.4e38f;
    int   bestj = 0;

    for (int base = 0; base < nr; base += RT) {
        __syncthreads();
        // Stage RT reference points into LDS as (x, y, z, |r|^2/2).
        for (int j = tid; j < RT; j += BQ) {
            const float rx = R[(size_t)(base + j) * 3 + 0];
            const float ry = R[(size_t)(base + j) * 3 + 1];
            const float rz = R[(size_t)(base + j) * 3 + 2];
            sref[j] = make_float4(rx, ry, rz, 0.5f * (rx * rx + ry * ry + rz * rz));
        }
        __syncthreads();

        #pragma unroll 8
        for (int j = 0; j < RT; ++j) {
            const float4 r = sref[j];            // wave-uniform addr -> LDS broadcast
            float t = __fmaf_rn(-qx, r.x, r.w);  // h - q.r  (argmin-equivalent score)
            t = __fmaf_rn(-qy, r.y, t);
            t = __fmaf_rn(-qz, r.z, t);
            const bool c = t < best;             // strict < : first-min tie-break,
            best  = c ? t : best;                // matches jnp.argmin
            bestj = c ? (base + j) : bestj;
        }
    }

    // Gather the NN point, fifth-power of component abs-differences.
    const float dx = qx - R[(size_t)bestj * 3 + 0];
    const float dy = qy - R[(size_t)bestj * 3 + 1];
    const float dz = qz - R[(size_t)bestj * 3 + 2];
    const float ax = fabsf(dx), ay = fabsf(dy), az = fabsf(dz);
    const float ax2 = ax * ax, ay2 = ay * ay, az2 = az * az;
    float s = ax2 * ax2 * ax + ay2 * ay2 * ay + az2 * az2 * az;

    // Block reduction: wave64 shuffle, then 4 partials through LDS.
    #pragma unroll
    for (int off = 32; off > 0; off >>= 1)
        s += __shfl_down(s, off, 64);
    const int wid = tid >> 6, lane = tid & 63;
    if (lane == 0) red[wid] = s;
    __syncthreads();
    if (tid == 0) {
        atomicAdd(&acc[b * 2 + dir], red[0] + red[1] + red[2] + red[3]);
    }
}

__global__ void chamfer_finalize_kernel(const float* __restrict__ acc,
                                        float* __restrict__ out)
{
    if (threadIdx.x == 0 && blockIdx.x == 0) {
        float total = 0.0f;
        #pragma unroll
        for (int b = 0; b < 8; ++b) {
            total += powf(acc[2 * b + 0], 0.2f);
            total += powf(acc[2 * b + 1], 0.2f);
        }
        *out = total * 0.125f;  // mean over B=8
    }
}

extern "C" void kernel_launch(void* const* d_in, const int* in_sizes, int n_in,
                              void* d_out, int out_size, void* d_ws, size_t ws_size,
                              hipStream_t stream)
{
    const float* x = (const float*)d_in[0];
    const float* y = (const float*)d_in[1];
    float* out = (float*)d_out;
    float* acc = (float*)d_ws;           // 16 floats: [b][dir] fifth-power sums

    const int N = in_sizes[0] / 24;      // B=8, C=3
    const int M = in_sizes[1] / 24;

    hipMemsetAsync(acc, 0, 16 * sizeof(float), stream);
    chamfer_nn_kernel<<<256, BQ, 0, stream>>>(x, y, acc, N, M);
    chamfer_finalize_kernel<<<1, 64, 0, stream>>>(acc, out);
}

// Round 2
// 112.736 us; speedup vs baseline: 1.5543x; 1.5543x over previous
//
#include <hip/hip_runtime.h>
#include <math.h>

// Chamfer p-norm loss (P=5), B=8, N=M=4096, C=3.
//  - argmin_j |q - r_j|^2 == argmin_j (|r_j|^2/2 - q.r_j); h_j precomputed at stage.
//  - sum_n pc^5 = sum_n sum_c |q_c - nn_c|^5 -> accumulate fifth powers, one
//    pow(.,0.2) per (batch,dir) at the end.
// R2: ref dimension split across 4 blocks (grid 256->1024, 4 waves/SIMD) to fix
// the round-1 latency bound (VALUBusy 38%, Occupancy 10%, 1 wave/SIMD).
// Partial argmins combined via atomicMin on an order-preserving packed
// (score<<32 | j) uint64 -> min == first-minimum tie-break (matches jnp.argmin).

#define BQ     256   // threads per block = queries per block
#define SPLITS 4     // ref-dimension splits per query tile
#define CH     1024  // refs per split chunk (16 KB LDS as float4)

__device__ __forceinline__ unsigned int float_ord(float f) {
    unsigned int u = __float_as_uint(f);
    return (u & 0x80000000u) ? ~u : (u | 0x80000000u);
}
__device__ __forceinline__ float ord_float(unsigned int u) {
    u = (u & 0x80000000u) ? (u & 0x7fffffffu) : ~u;
    return __uint_as_float(u);
}

// ---- main scan: one thread = one query, one block = one (query-tile, ref-split)
__global__ __launch_bounds__(BQ) void chamfer_nn_split_kernel(
    const float* __restrict__ x, const float* __restrict__ y,
    unsigned long long* __restrict__ packed, int N, int M)
{
    __shared__ float4 sref[CH];

    const int bid   = blockIdx.x;
    const int split = bid & (SPLITS - 1);
    const int qb    = bid / SPLITS;
    const int tile  = qb & 15;          // 16 query tiles of 256
    const int dir   = (qb >> 4) & 1;    // 0: q=x ref=y, 1: q=y ref=x
    const int b     = qb >> 5;          // batch

    const float* Q;
    const float* R;
    int nq, nr;
    if (dir == 0) { Q = x + (size_t)b * N * 3; R = y + (size_t)b * M * 3; nq = N; nr = M; }
    else          { Q = y + (size_t)b * M * 3; R = x + (size_t)b * N * 3; nq = M; nr = N; }

    const int tid  = threadIdx.x;
    const int q    = tile * BQ + tid;
    const int base = split * CH;

    // Stage this split's CH refs into LDS as (x, y, z, |r|^2/2).
    for (int j = tid; j < CH; j += BQ) {
        const float rx = R[(size_t)(base + j) * 3 + 0];
        const float ry = R[(size_t)(base + j) * 3 + 1];
        const float rz = R[(size_t)(base + j) * 3 + 2];
        sref[j] = make_float4(rx, ry, rz, 0.5f * (rx * rx + ry * ry + rz * rz));
    }
    __syncthreads();

    const float qx = Q[q * 3 + 0];
    const float qy = Q[q * 3 + 1];
    const float qz = Q[q * 3 + 2];

    float best  = 3.4e38f;
    int   bestj = base;

    #pragma unroll 8
    for (int j = 0; j < CH; ++j) {
        const float4 r = sref[j];            // wave-uniform addr -> LDS broadcast
        float t = __fmaf_rn(-qx, r.x, r.w);  // h - q.r  (argmin-equivalent score)
        t = __fmaf_rn(-qy, r.y, t);
        t = __fmaf_rn(-qz, r.z, t);
        const bool c = t < best;
        best  = c ? t : best;
        bestj = c ? (base + j) : bestj;
    }

    // Combine partials: min over packed (ordered-score, j) == first-min argmin.
    const unsigned long long p =
        ((unsigned long long)float_ord(best) << 32) | (unsigned int)bestj;
    const int gq = dir * (N) + 0;  // placeholder to keep compiler quiet
    (void)gq;
    const size_t slot = (size_t)dir * N + (size_t)b * 0;  // (unused path guard)
    (void)slot;
    const size_t idx = ((size_t)dir * 8 + b) * (size_t)N + q;  // N==M assumed
    atomicMin(&packed[idx], p);
    (void)nq;
}

// ---- decode winners, gather NN, accumulate fifth powers per (batch, dir)
__global__ __launch_bounds__(BQ) void chamfer_gather_kernel(
    const float* __restrict__ x, const float* __restrict__ y,
    const unsigned long long* __restrict__ packed,
    float* __restrict__ acc, int N, int M)
{
    __shared__ float red[4];

    const int tid = threadIdx.x;
    const size_t gq = (size_t)blockIdx.x * BQ + tid;
    const int dir = (int)(gq / ((size_t)8 * N));
    const size_t rem = gq - (size_t)dir * 8 * N;
    const int b = (int)(rem / N);
    const int q = (int)(rem - (size_t)b * N);

    const float* Q;
    const float* R;
    if (dir == 0) { Q = x + (size_t)b * N * 3; R = y + (size_t)b * M * 3; }
    else          { Q = y + (size_t)b * M * 3; R = x + (size_t)b * N * 3; }

    const int j = (int)(unsigned int)packed[gq];
    const float dx = Q[q * 3 + 0] - R[(size_t)j * 3 + 0];
    const float dy = Q[q * 3 + 1] - R[(size_t)j * 3 + 1];
    const float dz = Q[q * 3 + 2] - R[(size_t)j * 3 + 2];
    const float ax = fabsf(dx), ay = fabsf(dy), az = fabsf(dz);
    const float ax2 = ax * ax, ay2 = ay * ay, az2 = az * az;
    float s = ax2 * ax2 * ax + ay2 * ay2 * ay + az2 * az2 * az;

    #pragma unroll
    for (int off = 32; off > 0; off >>= 1)
        s += __shfl_down(s, off, 64);
    const int wid = tid >> 6, lane = tid & 63;
    if (lane == 0) red[wid] = s;
    __syncthreads();
    if (tid == 0)
        atomicAdd(&acc[b * 2 + dir], red[0] + red[1] + red[2] + red[3]);
}

__global__ void chamfer_finalize_kernel(const float* __restrict__ acc,
                                        float* __restrict__ out)
{
    if (threadIdx.x == 0 && blockIdx.x == 0) {
        float total = 0.0f;
        #pragma unroll
        for (int b = 0; b < 8; ++b) {
            total += powf(acc[2 * b + 0], 0.2f);
            total += powf(acc[2 * b + 1], 0.2f);
        }
        *out = total * 0.125f;  // mean over B=8
    }
}

// ---- round-1 fallback (single-kernel, no big workspace needed)
#define RT 2048
__global__ __launch_bounds__(BQ) void chamfer_nn_kernel(
    const float* __restrict__ x, const float* __restrict__ y,
    float* __restrict__ acc, int N, int M)
{
    __shared__ float4 sref[RT];
    __shared__ float red[4];

    const int bid  = blockIdx.x;
    const int tile = bid & 15;
    const int dir  = (bid >> 4) & 1;
    const int b    = bid >> 5;

    const float* Q; const float* R; int nr;
    if (dir == 0) { Q = x + (size_t)b * N * 3; R = y + (size_t)b * M * 3; nr = M; }
    else          { Q = y + (size_t)b * M * 3; R = x + (size_t)b * N * 3; nr = N; }

    const int tid = threadIdx.x;
    const int q   = tile * BQ + tid;
    const float qx = Q[q * 3 + 0], qy = Q[q * 3 + 1], qz = Q[q * 3 + 2];

    float best = 3.4e38f; int bestj = 0;
    for (int base = 0; base < nr; base += RT) {
        __syncthreads();
        for (int j = tid; j < RT; j += BQ) {
            const float rx = R[(size_t)(base + j) * 3 + 0];
            const float ry = R[(size_t)(base + j) * 3 + 1];
            const float rz = R[(size_t)(base + j) * 3 + 2];
            sref[j] = make_float4(rx, ry, rz, 0.5f * (rx * rx + ry * ry + rz * rz));
        }
        __syncthreads();
        #pragma unroll 8
        for (int j = 0; j < RT; ++j) {
            const float4 r = sref[j];
            float t = __fmaf_rn(-qx, r.x, r.w);
            t = __fmaf_rn(-qy, r.y, t);
            t = __fmaf_rn(-qz, r.z, t);
            const bool c = t < best;
            best = c ? t : best; bestj = c ? (base + j) : bestj;
        }
    }
    const float dx = qx - R[(size_t)bestj * 3 + 0];
    const float dy = qy - R[(size_t)bestj * 3 + 1];
    const float dz = qz - R[(size_t)bestj * 3 + 2];
    const float ax = fabsf(dx), ay = fabsf(dy), az = fabsf(dz);
    const float ax2 = ax * ax, ay2 = ay * ay, az2 = az * az;
    float s = ax2 * ax2 * ax + ay2 * ay2 * ay + az2 * az2 * az;
    #pragma unroll
    for (int off = 32; off > 0; off >>= 1) s += __shfl_down(s, off, 64);
    const int wid = tid >> 6, lane = tid & 63;
    if (lane == 0) red[wid] = s;
    __syncthreads();
    if (tid == 0) atomicAdd(&acc[b * 2 + dir], red[0] + red[1] + red[2] + red[3]);
}

extern "C" void kernel_launch(void* const* d_in, const int* in_sizes, int n_in,
                              void* d_out, int out_size, void* d_ws, size_t ws_size,
                              hipStream_t stream)
{
    const float* x = (const float*)d_in[0];
    const float* y = (const float*)d_in[1];
    float* out = (float*)d_out;

    const int N = in_sizes[0] / 24;  // B=8, C=3
    const int M = in_sizes[1] / 24;

    const size_t nQ = (size_t)2 * 8 * N;          // 65536 query slots
    const size_t packed_bytes = nQ * sizeof(unsigned long long);
    const size_t needed = packed_bytes + 16 * sizeof(float);

    if (ws_size >= needed && N == M && (N % (BQ * 16 / 16)) == 0) {
        unsigned long long* packed = (unsigned long long*)d_ws;
        float* acc = (float*)((char*)d_ws + packed_bytes);
        hipMemsetAsync(packed, 0xFF, packed_bytes, stream);   // max uint64
        hipMemsetAsync(acc, 0, 16 * sizeof(float), stream);
        const int qBlocks = (int)(nQ / BQ);                    // 256
        chamfer_nn_split_kernel<<<qBlocks * SPLITS, BQ, 0, stream>>>(x, y, packed, N, M);
        chamfer_gather_kernel<<<qBlocks, BQ, 0, stream>>>(x, y, packed, acc, N, M);
        chamfer_finalize_kernel<<<1, 64, 0, stream>>>(acc, out);
    } else {
        float* acc = (float*)d_ws;
        hipMemsetAsync(acc, 0, 16 * sizeof(float), stream);
        chamfer_nn_kernel<<<256, BQ, 0, stream>>>(x, y, acc, N, M);
        chamfer_finalize_kernel<<<1, 64, 0, stream>>>(acc, out);
    }
}